// Round 9
// baseline (325.339 us; speedup 1.0000x reference)
//
#include <hip/hip_runtime.h>

#define EPS 1e-5f

// ---- d_ws layout (float offsets unless noted) ----
#define W1OT 0          //   648  offset1_w [t*4+c][18] (c=3 zero-pad)
#define W1B  1024       //  2048 ushorts: conv1_w bf16 [n=64][k=32] (k=t*3+c, 27..31 zero)
#define W2T  4096       // 73728 ushorts: conv2_w bf16 FRAGMENT-LINEAR [t][ks][nt][lane][8]
#define W2OB 40960      // 18432 ushorts: offset2_w bf16 fragment-linear [t][ks][nt][q][r][8]
#define SC1  59392      //    64  bn1 scale
#define SH1  59456      //    64  bn1 shift (bias folded)
#define SC2  59520      //   128  bn2 scale
#define SH2  59648      //   128  bn2 shift (bias folded)
#define POOL 59776      //  4096  pooled sums (zeroed in prep)
#define XP   65536      // 524288  x as NHWC4 fp32 [b][hw][4] (ch3=0)
#define H1B  589824     // 8388608 ushorts: h1 bf16 NHWC [b][hw][64]
// end 4784128 floats = 19.1 MiB
#define W1B_U   2048    // ushort offsets
#define W2T_U   8192
#define W2OB_U  81920
#define H1B_U   1179648

typedef __attribute__((ext_vector_type(8))) short bhalf8;
typedef __attribute__((ext_vector_type(4))) float f32x4;
typedef __attribute__((ext_vector_type(4))) uint u32x4;

#define APAD 40    // def1 LDS k-row stride (ushorts): 80B, 16B-aligned, <=2-way

struct Tap { int i00, i01, i10, i11; float w00, w01, w10, w11; };

__device__ __forceinline__ Tap make_tap(float py, float px) {
    float y0f = floorf(py), x0f = floorf(px);
    float wy = py - y0f, wx = px - x0f;
    bool by0 = (y0f >= 0.f)  && (y0f < 64.f);
    bool by1 = (y0f >= -1.f) && (y0f < 63.f);
    bool bx0 = (x0f >= 0.f)  && (x0f < 64.f);
    bool bx1 = (x0f >= -1.f) && (x0f < 63.f);
    int y0 = min(max((int)y0f, 0), 63);
    int y1 = min(max((int)y0f + 1, 0), 63);
    int x0 = min(max((int)x0f, 0), 63);
    int x1 = min(max((int)x0f + 1, 0), 63);
    Tap tp;
    tp.i00 = y0 * 64 + x0; tp.i01 = y0 * 64 + x1;
    tp.i10 = y1 * 64 + x0; tp.i11 = y1 * 64 + x1;
    tp.w00 = (by0 && bx0) ? (1.f - wy) * (1.f - wx) : 0.f;
    tp.w01 = (by0 && bx1) ? (1.f - wy) * wx         : 0.f;
    tp.w10 = (by1 && bx0) ? wy * (1.f - wx)         : 0.f;
    tp.w11 = (by1 && bx1) ? wy * wx                 : 0.f;
    return tp;
}

__device__ __forceinline__ ushort f2bf(float f) {
    union { float f; uint u; } a; a.f = f;
    uint u = a.u;
    return (ushort)((u + 0x7fffu + ((u >> 16) & 1u)) >> 16);   // RNE
}

// packed bf16 convert: lo = bf16(a), hi = bf16(b) — hardware RNE, matches f2bf
__device__ __forceinline__ uint cvtpk_bf16(float a, float b) {
    uint r;
    asm("v_cvt_pk_bf16_f32 %0, %1, %2" : "=v"(r) : "v"(a), "v"(b));
    return r;
}

// bf16 pair expansion: even lanes (low halves) and odd lanes (high halves)
__device__ __forceinline__ f32x4 evenf(uint4 u) {
    union { uint u; float f; } a;
    f32x4 r;
    a.u = u.x << 16; r[0] = a.f;
    a.u = u.y << 16; r[1] = a.f;
    a.u = u.z << 16; r[2] = a.f;
    a.u = u.w << 16; r[3] = a.f;
    return r;
}
__device__ __forceinline__ f32x4 oddf(uint4 u) {
    union { uint u; float f; } a;
    f32x4 r;
    a.u = u.x & 0xffff0000u; r[0] = a.f;
    a.u = u.y & 0xffff0000u; r[1] = a.f;
    a.u = u.z & 0xffff0000u; r[2] = a.f;
    a.u = u.w & 0xffff0000u; r[3] = a.f;
    return r;
}

// ---- prep: weight transposes + BN folding + pool zero + x NHWC4 pack ----
__global__ __launch_bounds__(256) void k_prep(
    const float* __restrict__ x,
    const float* __restrict__ o1w, const float* __restrict__ c1w,
    const float* __restrict__ o2w, const float* __restrict__ c2w,
    const float* __restrict__ c1b, const float* __restrict__ g1,
    const float* __restrict__ be1, const float* __restrict__ m1,
    const float* __restrict__ v1,
    const float* __restrict__ c2b, const float* __restrict__ g2,
    const float* __restrict__ be2, const float* __restrict__ m2,
    const float* __restrict__ v2,
    float* __restrict__ ws) {
    int tid = blockIdx.x * 256 + threadIdx.x;
    ushort* wsu = (ushort*)ws;
    if (tid < 648) {                          // W1OT [t*4+c][18]
        int co = tid % 18, tc = tid / 18, c = tc & 3, t = tc >> 2;
        ws[W1OT + tid] = (c < 3) ? o1w[(co * 3 + c) * 9 + t] : 0.f;
    } else if (tid < 2696) {                  // W1B bf16 [n][k=32], k=t*3+c
        int i = tid - 648;
        int n = i >> 5, k = i & 31;
        float v = 0.f;
        if (k < 27) { int c = k % 3, t = k / 3; v = c1w[(n * 3 + c) * 9 + t]; }
        wsu[W1B_U + i] = f2bf(v);
    } else if (tid < 76424) {                 // W2T bf16 FRAGMENT-LINEAR
        int i = tid - 2696;                   // [t][ks][nt][lane][8]
        int j = i & 7, lane = (i >> 3) & 63, sub = i >> 9;
        int nt = sub & 7, ks = (sub >> 3) & 1, t = sub >> 4;
        int r = lane & 15, q = lane >> 4;
        int n = nt * 16 + r, c = ks * 32 + q * 8 + j;
        wsu[W2T_U + i] = f2bf(c2w[(n * 64 + c) * 9 + t]);
    } else if (tid < 94856) {                 // W2OB bf16 fragment-linear
        int i = tid - 76424;                  // [t][ks][nt][q][r][8]
        int j = i & 7, r = (i >> 3) & 15, q = (i >> 7) & 3;
        int nt = (i >> 9) & 1, ks = (i >> 10) & 1, t = i >> 11;
        int n = nt * 16 + r;
        int c = ks * 32 + q * 8 + j;
        float v = (n < 18) ? o2w[(n * 64 + c) * 9 + t] : 0.f;
        wsu[W2OB_U + i] = f2bf(v);
    } else if (tid < 94920) {
        int i = tid - 94856;
        float s = g1[i] * rsqrtf(v1[i] + EPS);
        ws[SC1 + i] = s;
        ws[SH1 + i] = (c1b[i] - m1[i]) * s + be1[i];
    } else if (tid < 95048) {
        int i = tid - 94920;
        float s = g2[i] * rsqrtf(v2[i] + EPS);
        ws[SC2 + i] = s;
        ws[SH2 + i] = (c2b[i] - m2[i]) * s + be2[i];
    } else if (tid < 99144) {
        ws[POOL + tid - 95048] = 0.f;
    } else if (tid < 230216) {                // XP pack: x NCHW -> NHWC4
        int i = tid - 99144;                  // = b*4096 + hw
        int b = i >> 12, hw = i & 4095;
        const float* xpp = x + (size_t)b * 3 * 4096 + hw;
        f32x4 o;
        o[0] = xpp[0]; o[1] = xpp[4096]; o[2] = xpp[8192]; o[3] = 0.f;
        *(f32x4*)(ws + XP + (size_t)i * 4) = o;
    }
}

// ---- fused offset-conv1 + deform conv1 (3->64) as MFMA implicit GEMM ----
__global__ __launch_bounds__(256, 4) void k_def1(
    const float* __restrict__ o1b, float* __restrict__ ws) {
    __shared__ ushort Alds[256 * APAD];       // 20 KB
    __shared__ ushort Blds[64 * APAD];        // 5 KB
    __shared__ float wo[648];
    __shared__ float scl[128];
    int tid = threadIdx.x;
    for (int i = tid; i < 648; i += 256) wo[i] = ws[W1OT + i];
    if (tid < 128) scl[tid] = ws[SC1 + tid];  // SC1[0..63], SH1 at +64
    {   // stage B: 64 rows x 32 ushorts -> padded rows
        const ushort* src = (const ushort*)ws + W1B_U;
        if (tid < 128) {
            int n = tid >> 1, half = (tid & 1) * 16;
            *(uint4*)(Blds + n * APAD + half)     = *(const uint4*)(src + n * 32 + half);
            *(uint4*)(Blds + n * APAD + half + 8) = *(const uint4*)(src + n * 32 + half + 8);
        }
    }
    int g = blockIdx.x;
    int b = (g & 7) * 4 + ((g >> 3) & 3);     // XCD swizzle: 4 images/XCD
    int row0 = (g >> 5) * 4;
    int h = row0 + (tid >> 6), w = tid & 63;
    const float* xp = ws + XP + (size_t)b * 16384;

    // ---- phase A: off1 conv ----
    float off[18];
#pragma unroll
    for (int i = 0; i < 18; ++i) off[i] = o1b[i];
    __syncthreads();                          // wo staged
#pragma unroll
    for (int t = 0; t < 9; ++t) {
        int yy = h + t / 3 - 1, xx = w + t % 3 - 1;
        f32x4 pv = (f32x4)0.f;
        if (yy >= 0 && yy < 64 && xx >= 0 && xx < 64)
            pv = *(const f32x4*)(xp + (yy * 64 + xx) * 4);
#pragma unroll
        for (int c = 0; c < 3; ++c) {
            const float* wp = wo + (t * 4 + c) * 18;
#pragma unroll
            for (int co = 0; co < 18; ++co) off[co] += pv[c] * wp[co];
        }
    }
    // gathers -> bf16 k-row
    ushort ob[32];
#pragma unroll
    for (int i = 0; i < 32; ++i) ob[i] = 0;
#pragma unroll
    for (int t = 0; t < 9; ++t) {
        Tap tp = make_tap((float)(h + t / 3 - 1) + off[2 * t],
                          (float)(w + t % 3 - 1) + off[2 * t + 1]);
        f32x4 c00 = *(const f32x4*)(xp + tp.i00 * 4);
        f32x4 c01 = *(const f32x4*)(xp + tp.i01 * 4);
        f32x4 c10 = *(const f32x4*)(xp + tp.i10 * 4);
        f32x4 c11 = *(const f32x4*)(xp + tp.i11 * 4);
        f32x4 vt = tp.w00 * c00 + tp.w01 * c01 + tp.w10 * c10 + tp.w11 * c11;
        ob[t * 3 + 0] = f2bf(vt[0]);
        ob[t * 3 + 1] = f2bf(vt[1]);
        ob[t * 3 + 2] = f2bf(vt[2]);
    }
    {
        ushort* ar = Alds + tid * APAD;
#pragma unroll
        for (int i = 0; i < 4; ++i)
            *(uint4*)(ar + i * 8) = *(const uint4*)(ob + i * 8);
    }
    __syncthreads();

    // ---- phase B: MFMA, wave = px[wv*64 .. +64) x all 64 couts ----
    int lane = tid & 63, wv = tid >> 6;
    int r = lane & 15, q = lane >> 4;
    bhalf8 bf[4];
#pragma unroll
    for (int nt = 0; nt < 4; ++nt)
        bf[nt] = *(const bhalf8*)(Blds + (nt * 16 + r) * APAD + q * 8);
    f32x4 acc[4][4];
#pragma unroll
    for (int mt = 0; mt < 4; ++mt) {
        bhalf8 af = *(const bhalf8*)(Alds + (wv * 64 + mt * 16 + r) * APAD + q * 8);
#pragma unroll
        for (int nt = 0; nt < 4; ++nt)
            acc[mt][nt] = __builtin_amdgcn_mfma_f32_16x16x32_bf16(af, bf[nt], (f32x4)0.f, 0, 0, 0);
    }
    // ---- epilogue: BN + ReLU -> h1 bf16 ----
    ushort* hb = (ushort*)ws + H1B_U + (size_t)(b * 4096 + row0 * 64) * 64;
#pragma unroll
    for (int nt = 0; nt < 4; ++nt) {
        int col = nt * 16 + r;
        float s0 = scl[col], s1 = scl[64 + col];
#pragma unroll
        for (int mt = 0; mt < 4; ++mt) {
            int pxl = wv * 64 + mt * 16 + q * 4;
#pragma unroll
            for (int rr = 0; rr < 4; ++rr)
                hb[(size_t)(pxl + rr) * 64 + col] =
                    f2bf(fmaxf(acc[mt][nt][rr] * s0 + s1, 0.f));
        }
    }
}

// ---- FUSED offset-conv2 + deform conv2 (64->128) + BN + ReLU + pool ----
// v9: BARRIER-FREE streaming. B-fragments for the deform GEMM read
// DIRECTLY from global fragment-linear W2T (1KB contiguous per wave-load,
// L2-resident 144KB shared by all blocks) — no Bd, no global_load_lds, no
// vmcnt asm, no phase-2 barriers. Each wave streams its 10 taps
// independently with a 1-tap-ahead register gather pipeline (gq[2]).
// LDS = offL only (4608B). One barrier in the whole kernel.
__global__ __launch_bounds__(256, 4) void k_def2(
    const float* __restrict__ o2b, float* __restrict__ ws) {
    __shared__ float offL[64 * 18];           // 4608 B
    int g = blockIdx.x;                       // 2048 blocks
    int b = (g & 7) * 4 + ((g >> 3) & 3);     // 4 images per XCD
    int row = g >> 5;
    int tid = threadIdx.x, lane = tid & 63, wv = tid >> 6;
    int r = lane & 15, q = lane >> 4;
    int px = wv * 16 + r;
    const ushort* hb = (const ushort*)ws + H1B_U + (size_t)b * 262144;
    const ushort* btl = (const ushort*)ws + W2OB_U + lane * 8;   // off2 B frags
    const ushort* wtl = (const ushort*)ws + W2T_U + lane * 8;    // conv2 B frags

    // ---- phase 1: off2 GEMM, B fragment-linear from global ----
    f32x4 acc2[2];
    acc2[0] = (f32x4)0.f; acc2[1] = (f32x4)0.f;
#pragma unroll
    for (int t = 0; t < 9; ++t) {
        int yy = row + t / 3 - 1;
        int xx = px + t % 3 - 1;
        bool val = (yy >= 0 && yy < 64 && xx >= 0 && xx < 64);
        int yyc = min(max(yy, 0), 63), xxc = min(max(xx, 0), 63);
        const ushort* ap = hb + (size_t)(yyc * 64 + xxc) * 64 + q * 8;
#pragma unroll
        for (int ks = 0; ks < 2; ++ks) {
            bhalf8 af = val ? *(const bhalf8*)(ap + ks * 32) : (bhalf8)(short)0;
#pragma unroll
            for (int nt = 0; nt < 2; ++nt) {
                bhalf8 bf = *(const bhalf8*)(btl + (size_t)((t * 2 + ks) * 2 + nt) * 512);
                acc2[nt] = __builtin_amdgcn_mfma_f32_16x16x32_bf16(af, bf, acc2[nt], 0, 0, 0);
            }
        }
    }
#pragma unroll
    for (int nt = 0; nt < 2; ++nt) {
        int n = nt * 16 + r;
        if (n < 18) {
            float bias = o2b[n];
#pragma unroll
            for (int rr = 0; rr < 4; ++rr)
                offL[(wv * 16 + q * 4 + rr) * 18 + n] = acc2[nt][rr] + bias;
        }
    }
    __syncthreads();                          // offL visible — ONLY barrier
    float2 o2v[9];
#pragma unroll
    for (int t = 0; t < 9; ++t)
        o2v[t] = *(const float2*)(offL + px * 18 + 2 * t);

    // ---- phase 2: streaming deform conv2, no barriers ----
    f32x4 acc[8];
#pragma unroll
    for (int j = 0; j < 8; ++j) acc[j] = (f32x4)0.f;

    Tap tp[2];
    uint4 gq[2][8];
    {   // tap-0 gathers
        tp[0] = make_tap((float)(row - 1) + o2v[0].x, (float)(px - 1) + o2v[0].y);
        int o00 = tp[0].i00 * 64 + q * 8;
        int o01 = tp[0].i01 * 64 + q * 8;
        int o10 = tp[0].i10 * 64 + q * 8;
        int o11 = tp[0].i11 * 64 + q * 8;
        gq[0][0] = *(const uint4*)(hb + o00);
        gq[0][1] = *(const uint4*)(hb + o01);
        gq[0][2] = *(const uint4*)(hb + o10);
        gq[0][3] = *(const uint4*)(hb + o11);
        gq[0][4] = *(const uint4*)(hb + o00 + 32);
        gq[0][5] = *(const uint4*)(hb + o01 + 32);
        gq[0][6] = *(const uint4*)(hb + o10 + 32);
        gq[0][7] = *(const uint4*)(hb + o11 + 32);
    }

#pragma unroll
    for (int t = 0; t < 9; ++t) {
        const int cur = t & 1, nxt = (t + 1) & 1;
        if (t < 8) {
            // gathers(t+1): issued before consuming gq[cur]; waves proceed
            // independently (no barrier), so these hide under tap t's
            // interp+MFMA regardless of other waves' progress.
            tp[nxt] = make_tap((float)(row + (t + 1) / 3 - 1) + o2v[t + 1].x,
                               (float)(px + (t + 1) % 3 - 1) + o2v[t + 1].y);
            int o00 = tp[nxt].i00 * 64 + q * 8;
            int o01 = tp[nxt].i01 * 64 + q * 8;
            int o10 = tp[nxt].i10 * 64 + q * 8;
            int o11 = tp[nxt].i11 * 64 + q * 8;
            gq[nxt][0] = *(const uint4*)(hb + o00);
            gq[nxt][1] = *(const uint4*)(hb + o01);
            gq[nxt][2] = *(const uint4*)(hb + o10);
            gq[nxt][3] = *(const uint4*)(hb + o11);
            gq[nxt][4] = *(const uint4*)(hb + o00 + 32);
            gq[nxt][5] = *(const uint4*)(hb + o01 + 32);
            gq[nxt][6] = *(const uint4*)(hb + o10 + 32);
            gq[nxt][7] = *(const uint4*)(hb + o11 + 32);
        }
        float w00 = tp[cur].w00, w01 = tp[cur].w01;
        float w10 = tp[cur].w10, w11 = tp[cur].w11;
        // interp ks=0 -> af0, MFMA with global B frags; then ks=1
        bhalf8 af0, af1;
        {
            f32x4 ve = w00 * evenf(gq[cur][0]) + w01 * evenf(gq[cur][1])
                     + w10 * evenf(gq[cur][2]) + w11 * evenf(gq[cur][3]);
            f32x4 vo = w00 * oddf(gq[cur][0]) + w01 * oddf(gq[cur][1])
                     + w10 * oddf(gq[cur][2]) + w11 * oddf(gq[cur][3]);
            u32x4 uu;
            uu[0] = cvtpk_bf16(ve[0], vo[0]);
            uu[1] = cvtpk_bf16(ve[1], vo[1]);
            uu[2] = cvtpk_bf16(ve[2], vo[2]);
            uu[3] = cvtpk_bf16(ve[3], vo[3]);
            af0 = __builtin_bit_cast(bhalf8, uu);
        }
        {
            f32x4 ve = w00 * evenf(gq[cur][4]) + w01 * evenf(gq[cur][5])
                     + w10 * evenf(gq[cur][6]) + w11 * evenf(gq[cur][7]);
            f32x4 vo = w00 * oddf(gq[cur][4]) + w01 * oddf(gq[cur][5])
                     + w10 * oddf(gq[cur][6]) + w11 * oddf(gq[cur][7]);
            u32x4 uu;
            uu[0] = cvtpk_bf16(ve[0], vo[0]);
            uu[1] = cvtpk_bf16(ve[1], vo[1]);
            uu[2] = cvtpk_bf16(ve[2], vo[2]);
            uu[3] = cvtpk_bf16(ve[3], vo[3]);
            af1 = __builtin_bit_cast(bhalf8, uu);
        }
#pragma unroll
        for (int nt = 0; nt < 8; ++nt) {
            bhalf8 bf = *(const bhalf8*)(wtl + (size_t)((t * 2 + 0) * 8 + nt) * 512);
            acc[nt] = __builtin_amdgcn_mfma_f32_16x16x32_bf16(af0, bf, acc[nt], 0, 0, 0);
        }
#pragma unroll
        for (int nt = 0; nt < 8; ++nt) {
            bhalf8 bf = *(const bhalf8*)(wtl + (size_t)((t * 2 + 1) * 8 + nt) * 512);
            acc[nt] = __builtin_amdgcn_mfma_f32_16x16x32_bf16(af1, bf, acc[nt], 0, 0, 0);
        }
    }
    // epilogue: BN + ReLU + pool (h2 never materialized)
    const float* sc = ws + SC2;
    const float* sh = ws + SH2;
    float* pool = ws + POOL;
#pragma unroll
    for (int nt = 0; nt < 8; ++nt) {
        int col = nt * 16 + r;
        float s0 = sc[col], s1 = sh[col];
        float s = 0.f;
#pragma unroll
        for (int rr = 0; rr < 4; ++rr)
            s += fmaxf(acc[nt][rr] * s0 + s1, 0.f);
        s += __shfl_xor(s, 16);
        s += __shfl_xor(s, 32);
        if (lane < 16) atomicAdd(&pool[b * 128 + col], s);
    }
}

// ---- fused fc1+relu+fc2 ----
__global__ __launch_bounds__(256) void k_fc(
    const float* __restrict__ w1, const float* __restrict__ b1,
    const float* __restrict__ w2, const float* __restrict__ b2,
    const float* __restrict__ ws, float* __restrict__ out) {
    int b = blockIdx.x, o = threadIdx.x;
    __shared__ float pl[128];
    __shared__ float hl[256];
    if (o < 128) pl[o] = ws[POOL + b * 128 + o] * (1.f / 4096.f);
    __syncthreads();
    float s = b1[o];
    const float* wp = w1 + o * 128;
#pragma unroll 8
    for (int c = 0; c < 128; ++c) s += pl[c] * wp[c];
    hl[o] = fmaxf(s, 0.f);
    __syncthreads();
    if (o < 200) {
        float s2 = b2[o];
        const float* wp2 = w2 + o * 256;
#pragma unroll 8
        for (int c = 0; c < 256; ++c) s2 += hl[c] * wp2[c];
        out[b * 200 + o] = s2;
    }
}

extern "C" void kernel_launch(void* const* d_in, const int* in_sizes, int n_in,
                              void* d_out, int out_size, void* d_ws, size_t ws_size,
                              hipStream_t stream) {
    const float* x   = (const float*)d_in[0];
    const float* o1w = (const float*)d_in[1];
    const float* o1b = (const float*)d_in[2];
    const float* c1w = (const float*)d_in[3];
    const float* c1b = (const float*)d_in[4];
    const float* g1  = (const float*)d_in[5];
    const float* be1 = (const float*)d_in[6];
    const float* m1  = (const float*)d_in[7];
    const float* v1  = (const float*)d_in[8];
    const float* o2w = (const float*)d_in[9];
    const float* o2b = (const float*)d_in[10];
    const float* c2w = (const float*)d_in[11];
    const float* c2b = (const float*)d_in[12];
    const float* g2  = (const float*)d_in[13];
    const float* be2 = (const float*)d_in[14];
    const float* m2  = (const float*)d_in[15];
    const float* v2  = (const float*)d_in[16];
    const float* f1w = (const float*)d_in[17];
    const float* f1b = (const float*)d_in[18];
    const float* f2w = (const float*)d_in[19];
    const float* f2b = (const float*)d_in[20];
    float* ws  = (float*)d_ws;
    float* out = (float*)d_out;

    k_prep<<<900, 256, 0, stream>>>(x, o1w, c1w, o2w, c2w,
                                    c1b, g1, be1, m1, v1,
                                    c2b, g2, be2, m2, v2, ws);
    k_def1<<<512, 256, 0, stream>>>(o1b, ws);
    k_def2<<<2048, 256, 0, stream>>>(o2b, ws);
    k_fc<<<32, 256, 0, stream>>>(f1w, f1b, f2w, f2b, ws, out);
}

// Round 10
// 284.918 us; speedup vs baseline: 1.1419x; 1.1419x over previous
//
#include <hip/hip_runtime.h>

#define EPS 1e-5f

// ---- d_ws layout (float offsets unless noted) ----
#define W1OT 0          //   648  offset1_w [t*4+c][18] (c=3 zero-pad)
#define W1B  1024       //  2048 ushorts: conv1_w bf16 [n=64][k=32] (k=t*3+c, 27..31 zero)
#define W2T  4096       // 73728 ushorts: conv2_w bf16 [t][n=cout128][c64]
#define W2OB 40960      // 18432 ushorts: offset2_w bf16 fragment-linear [t][ks][nt][q][r][8]
#define SC1  59392      //    64  bn1 scale
#define SH1  59456      //    64  bn1 shift (bias folded)
#define SC2  59520      //   128  bn2 scale
#define SH2  59648      //   128  bn2 shift (bias folded)
#define POOL 59776      //  4096  pooled sums (zeroed in prep)
#define XP   65536      // 524288  x as NHWC4 fp32 [b][hw][4] (ch3=0)
#define H1B  589824     // 8388608 ushorts: h1 bf16 NHWC [b][hw][64]
// end 4784128 floats = 19.1 MiB
#define W1B_U   2048    // ushort offsets
#define W2T_U   8192
#define W2OB_U  81920
#define H1B_U   1179648

typedef __attribute__((ext_vector_type(8))) short bhalf8;
typedef __attribute__((ext_vector_type(4))) float f32x4;
typedef __attribute__((ext_vector_type(4))) uint u32x4;

#define APAD 40    // def1 LDS k-row stride (ushorts): 80B, 16B-aligned, <=2-way

struct Tap { int i00, i01, i10, i11; float w00, w01, w10, w11; };

__device__ __forceinline__ Tap make_tap(float py, float px) {
    float y0f = floorf(py), x0f = floorf(px);
    float wy = py - y0f, wx = px - x0f;
    bool by0 = (y0f >= 0.f)  && (y0f < 64.f);
    bool by1 = (y0f >= -1.f) && (y0f < 63.f);
    bool bx0 = (x0f >= 0.f)  && (x0f < 64.f);
    bool bx1 = (x0f >= -1.f) && (x0f < 63.f);
    int y0 = min(max((int)y0f, 0), 63);
    int y1 = min(max((int)y0f + 1, 0), 63);
    int x0 = min(max((int)x0f, 0), 63);
    int x1 = min(max((int)x0f + 1, 0), 63);
    Tap tp;
    tp.i00 = y0 * 64 + x0; tp.i01 = y0 * 64 + x1;
    tp.i10 = y1 * 64 + x0; tp.i11 = y1 * 64 + x1;
    tp.w00 = (by0 && bx0) ? (1.f - wy) * (1.f - wx) : 0.f;
    tp.w01 = (by0 && bx1) ? (1.f - wy) * wx         : 0.f;
    tp.w10 = (by1 && bx0) ? wy * (1.f - wx)         : 0.f;
    tp.w11 = (by1 && bx1) ? wy * wx                 : 0.f;
    return tp;
}

__device__ __forceinline__ ushort f2bf(float f) {
    union { float f; uint u; } a; a.f = f;
    uint u = a.u;
    return (ushort)((u + 0x7fffu + ((u >> 16) & 1u)) >> 16);   // RNE
}

// packed bf16 convert: lo = bf16(a), hi = bf16(b) — hardware RNE, matches f2bf
__device__ __forceinline__ uint cvtpk_bf16(float a, float b) {
    uint r;
    asm("v_cvt_pk_bf16_f32 %0, %1, %2" : "=v"(r) : "v"(a), "v"(b));
    return r;
}

// bf16 pair expansion: even lanes (low halves) and odd lanes (high halves)
__device__ __forceinline__ f32x4 evenf(uint4 u) {
    union { uint u; float f; } a;
    f32x4 r;
    a.u = u.x << 16; r[0] = a.f;
    a.u = u.y << 16; r[1] = a.f;
    a.u = u.z << 16; r[2] = a.f;
    a.u = u.w << 16; r[3] = a.f;
    return r;
}
__device__ __forceinline__ f32x4 oddf(uint4 u) {
    union { uint u; float f; } a;
    f32x4 r;
    a.u = u.x & 0xffff0000u; r[0] = a.f;
    a.u = u.y & 0xffff0000u; r[1] = a.f;
    a.u = u.z & 0xffff0000u; r[2] = a.f;
    a.u = u.w & 0xffff0000u; r[3] = a.f;
    return r;
}

// async global -> LDS, 16B per lane (dest = uniform base + lane*16)
__device__ __forceinline__ void gl_lds16(const void* g, void* l) {
    __builtin_amdgcn_global_load_lds(
        (const __attribute__((address_space(1))) unsigned int*)g,
        (__attribute__((address_space(3))) unsigned int*)l, 16, 0, 0);
}

// ---- prep: weight transposes + BN folding + pool zero + x NHWC4 pack ----
__global__ __launch_bounds__(256) void k_prep(
    const float* __restrict__ x,
    const float* __restrict__ o1w, const float* __restrict__ c1w,
    const float* __restrict__ o2w, const float* __restrict__ c2w,
    const float* __restrict__ c1b, const float* __restrict__ g1,
    const float* __restrict__ be1, const float* __restrict__ m1,
    const float* __restrict__ v1,
    const float* __restrict__ c2b, const float* __restrict__ g2,
    const float* __restrict__ be2, const float* __restrict__ m2,
    const float* __restrict__ v2,
    float* __restrict__ ws) {
    int tid = blockIdx.x * 256 + threadIdx.x;
    ushort* wsu = (ushort*)ws;
    if (tid < 648) {                          // W1OT [t*4+c][18]
        int co = tid % 18, tc = tid / 18, c = tc & 3, t = tc >> 2;
        ws[W1OT + tid] = (c < 3) ? o1w[(co * 3 + c) * 9 + t] : 0.f;
    } else if (tid < 2696) {                  // W1B bf16 [n][k=32], k=t*3+c
        int i = tid - 648;
        int n = i >> 5, k = i & 31;
        float v = 0.f;
        if (k < 27) { int c = k % 3, t = k / 3; v = c1w[(n * 3 + c) * 9 + t]; }
        wsu[W1B_U + i] = f2bf(v);
    } else if (tid < 76424) {                 // W2T bf16 [t][n][c]
        int i = tid - 2696;
        int c = i & 63, n = (i >> 6) & 127, t = i >> 13;
        wsu[W2T_U + i] = f2bf(c2w[(n * 64 + c) * 9 + t]);
    } else if (tid < 94856) {                 // W2OB bf16 fragment-linear
        int i = tid - 76424;                  // [t][ks][nt][q][r][8]
        int j = i & 7, r = (i >> 3) & 15, q = (i >> 7) & 3;
        int nt = (i >> 9) & 1, ks = (i >> 10) & 1, t = i >> 11;
        int n = nt * 16 + r;
        int c = ks * 32 + q * 8 + j;
        float v = (n < 18) ? o2w[(n * 64 + c) * 9 + t] : 0.f;
        wsu[W2OB_U + i] = f2bf(v);
    } else if (tid < 94920) {
        int i = tid - 94856;
        float s = g1[i] * rsqrtf(v1[i] + EPS);
        ws[SC1 + i] = s;
        ws[SH1 + i] = (c1b[i] - m1[i]) * s + be1[i];
    } else if (tid < 95048) {
        int i = tid - 94920;
        float s = g2[i] * rsqrtf(v2[i] + EPS);
        ws[SC2 + i] = s;
        ws[SH2 + i] = (c2b[i] - m2[i]) * s + be2[i];
    } else if (tid < 99144) {
        ws[POOL + tid - 95048] = 0.f;
    } else if (tid < 230216) {                // XP pack: x NCHW -> NHWC4
        int i = tid - 99144;                  // = b*4096 + hw
        int b = i >> 12, hw = i & 4095;
        const float* xpp = x + (size_t)b * 3 * 4096 + hw;
        f32x4 o;
        o[0] = xpp[0]; o[1] = xpp[4096]; o[2] = xpp[8192]; o[3] = 0.f;
        *(f32x4*)(ws + XP + (size_t)i * 4) = o;
    }
}

// ---- fused offset-conv1 + deform conv1 (3->64) as MFMA implicit GEMM ----
__global__ __launch_bounds__(256, 4) void k_def1(
    const float* __restrict__ o1b, float* __restrict__ ws) {
    __shared__ ushort Alds[256 * APAD];       // 20 KB
    __shared__ ushort Blds[64 * APAD];        // 5 KB
    __shared__ float wo[648];
    __shared__ float scl[128];
    int tid = threadIdx.x;
    for (int i = tid; i < 648; i += 256) wo[i] = ws[W1OT + i];
    if (tid < 128) scl[tid] = ws[SC1 + tid];  // SC1[0..63], SH1 at +64
    {   // stage B: 64 rows x 32 ushorts -> padded rows
        const ushort* src = (const ushort*)ws + W1B_U;
        if (tid < 128) {
            int n = tid >> 1, half = (tid & 1) * 16;
            *(uint4*)(Blds + n * APAD + half)     = *(const uint4*)(src + n * 32 + half);
            *(uint4*)(Blds + n * APAD + half + 8) = *(const uint4*)(src + n * 32 + half + 8);
        }
    }
    int g = blockIdx.x;
    int b = (g & 7) * 4 + ((g >> 3) & 3);     // XCD swizzle: 4 images/XCD
    int row0 = (g >> 5) * 4;
    int h = row0 + (tid >> 6), w = tid & 63;
    const float* xp = ws + XP + (size_t)b * 16384;

    // ---- phase A: off1 conv ----
    float off[18];
#pragma unroll
    for (int i = 0; i < 18; ++i) off[i] = o1b[i];
    __syncthreads();                          // wo staged
#pragma unroll
    for (int t = 0; t < 9; ++t) {
        int yy = h + t / 3 - 1, xx = w + t % 3 - 1;
        f32x4 pv = (f32x4)0.f;
        if (yy >= 0 && yy < 64 && xx >= 0 && xx < 64)
            pv = *(const f32x4*)(xp + (yy * 64 + xx) * 4);
#pragma unroll
        for (int c = 0; c < 3; ++c) {
            const float* wp = wo + (t * 4 + c) * 18;
#pragma unroll
            for (int co = 0; co < 18; ++co) off[co] += pv[c] * wp[co];
        }
    }
    // gathers -> bf16 k-row
    ushort ob[32];
#pragma unroll
    for (int i = 0; i < 32; ++i) ob[i] = 0;
#pragma unroll
    for (int t = 0; t < 9; ++t) {
        Tap tp = make_tap((float)(h + t / 3 - 1) + off[2 * t],
                          (float)(w + t % 3 - 1) + off[2 * t + 1]);
        f32x4 c00 = *(const f32x4*)(xp + tp.i00 * 4);
        f32x4 c01 = *(const f32x4*)(xp + tp.i01 * 4);
        f32x4 c10 = *(const f32x4*)(xp + tp.i10 * 4);
        f32x4 c11 = *(const f32x4*)(xp + tp.i11 * 4);
        f32x4 vt = tp.w00 * c00 + tp.w01 * c01 + tp.w10 * c10 + tp.w11 * c11;
        ob[t * 3 + 0] = f2bf(vt[0]);
        ob[t * 3 + 1] = f2bf(vt[1]);
        ob[t * 3 + 2] = f2bf(vt[2]);
    }
    {
        ushort* ar = Alds + tid * APAD;
#pragma unroll
        for (int i = 0; i < 4; ++i)
            *(uint4*)(ar + i * 8) = *(const uint4*)(ob + i * 8);
    }
    __syncthreads();

    // ---- phase B: MFMA, wave = px[wv*64 .. +64) x all 64 couts ----
    int lane = tid & 63, wv = tid >> 6;
    int r = lane & 15, q = lane >> 4;
    bhalf8 bf[4];
#pragma unroll
    for (int nt = 0; nt < 4; ++nt)
        bf[nt] = *(const bhalf8*)(Blds + (nt * 16 + r) * APAD + q * 8);
    f32x4 acc[4][4];
#pragma unroll
    for (int mt = 0; mt < 4; ++mt) {
        bhalf8 af = *(const bhalf8*)(Alds + (wv * 64 + mt * 16 + r) * APAD + q * 8);
#pragma unroll
        for (int nt = 0; nt < 4; ++nt)
            acc[mt][nt] = __builtin_amdgcn_mfma_f32_16x16x32_bf16(af, bf[nt], (f32x4)0.f, 0, 0, 0);
    }
    // ---- epilogue: BN + ReLU -> h1 bf16 ----
    ushort* hb = (ushort*)ws + H1B_U + (size_t)(b * 4096 + row0 * 64) * 64;
#pragma unroll
    for (int nt = 0; nt < 4; ++nt) {
        int col = nt * 16 + r;
        float s0 = scl[col], s1 = scl[64 + col];
#pragma unroll
        for (int mt = 0; mt < 4; ++mt) {
            int pxl = wv * 64 + mt * 16 + q * 4;
#pragma unroll
            for (int rr = 0; rr < 4; ++rr)
                hb[(size_t)(pxl + rr) * 64 + col] =
                    f2bf(fmaxf(acc[mt][nt][rr] * s0 + s1, 0.f));
        }
    }
}

// ---- FUSED offset-conv2 + deform conv2 (64->128) + BN + ReLU + pool ----
// v10 = v6 (best: 111.7us) + s_setprio(1) around the MFMA clusters (T5).
// v6 recap: single barrier per tap; stage(t+1) AFTER the barrier (the
// vmcnt(8)-then-barrier publishes stage(t) and doubles as the WAR guard);
// gathers(t+1) ride across the barrier; B streamed via LDS (lgkmcnt path,
// separate from gather vmcnt — R9 proved merging them costs 46us).
__global__ __launch_bounds__(256, 4) void k_def2(
    const float* __restrict__ o2b, float* __restrict__ ws) {
    __shared__ __align__(16) char smem[37376];
    float* offL = (float*)(smem + 32768);     // 64 px * 18 = 4608B
    int g = blockIdx.x;
    int b = (g & 7) * 4 + ((g >> 3) & 3);     // 4 images per XCD
    int row = g >> 5;
    int tid = threadIdx.x, lane = tid & 63, wv = tid >> 6;
    int r = lane & 15, q = lane >> 4;
    int px = wv * 16 + r;
    const ushort* hb = (const ushort*)ws + H1B_U + (size_t)b * 262144;
    const ushort* wB = (const ushort*)ws + W2T_U;
    const ushort* btl = (const ushort*)ws + W2OB_U + lane * 8;
    // per-lane swizzled stage source offsets (invariant across taps)
    int sOff[4];
#pragma unroll
    for (int i = 0; i < 4; ++i) {
        int lin = wv * 4096 + i * 1024 + lane * 16;
        sOff[i] = lin ^ (((lin >> 7) & 7) << 4);
    }
    // stage tap-0 weights into Bd[0]; phase 1 hides the latency and its
    // trailing __syncthreads() drains vmcnt(0) => Bd[0] complete.
#pragma unroll
    for (int i = 0; i < 4; ++i)
        gl_lds16((const char*)wB + sOff[i], smem + wv * 4096 + i * 1024);

    // ---- phase 1: off2 GEMM, B fragment-linear from global ----
    f32x4 acc2[2];
    acc2[0] = (f32x4)0.f; acc2[1] = (f32x4)0.f;
#pragma unroll
    for (int t = 0; t < 9; ++t) {
        int yy = row + t / 3 - 1;
        int xx = px + t % 3 - 1;
        bool val = (yy >= 0 && yy < 64 && xx >= 0 && xx < 64);
        int yyc = min(max(yy, 0), 63), xxc = min(max(xx, 0), 63);
        const ushort* ap = hb + (size_t)(yyc * 64 + xxc) * 64 + q * 8;
#pragma unroll
        for (int ks = 0; ks < 2; ++ks) {
            bhalf8 af = val ? *(const bhalf8*)(ap + ks * 32) : (bhalf8)(short)0;
#pragma unroll
            for (int nt = 0; nt < 2; ++nt) {
                bhalf8 bf = *(const bhalf8*)(btl + (size_t)((t * 2 + ks) * 2 + nt) * 512);
                acc2[nt] = __builtin_amdgcn_mfma_f32_16x16x32_bf16(af, bf, acc2[nt], 0, 0, 0);
            }
        }
    }
#pragma unroll
    for (int nt = 0; nt < 2; ++nt) {
        int n = nt * 16 + r;
        if (n < 18) {
            float bias = o2b[n];
#pragma unroll
            for (int rr = 0; rr < 4; ++rr)
                offL[(wv * 16 + q * 4 + rr) * 18 + n] = acc2[nt][rr] + bias;
        }
    }
    __syncthreads();   // offL visible; drains stage(0) (vmcnt(0) at barrier)

    // ---- phase 2: pipelined deform conv2, ONE barrier per tap ----
    f32x4 acc[8];
#pragma unroll
    for (int j = 0; j < 8; ++j) acc[j] = (f32x4)0.f;

    Tap tp[2];
    uint4 gq[2][8];
    {   // tap-0 taps + gathers (after syncthreads: offL ready)
        float oy = offL[px * 18 + 0];
        float ox = offL[px * 18 + 1];
        tp[0] = make_tap((float)(row - 1) + oy, (float)(px - 1) + ox);
        int o00 = tp[0].i00 * 64 + q * 8;
        int o01 = tp[0].i01 * 64 + q * 8;
        int o10 = tp[0].i10 * 64 + q * 8;
        int o11 = tp[0].i11 * 64 + q * 8;
        gq[0][0] = *(const uint4*)(hb + o00);
        gq[0][1] = *(const uint4*)(hb + o01);
        gq[0][2] = *(const uint4*)(hb + o10);
        gq[0][3] = *(const uint4*)(hb + o11);
        gq[0][4] = *(const uint4*)(hb + o00 + 32);
        gq[0][5] = *(const uint4*)(hb + o01 + 32);
        gq[0][6] = *(const uint4*)(hb + o10 + 32);
        gq[0][7] = *(const uint4*)(hb + o11 + 32);
    }

#pragma unroll
    for (int t = 0; t < 9; ++t) {
        const int cur = t & 1, nxt = (t + 1) & 1;
        if (t < 8) {
            // gathers(t+1) — issued first so they ride across the barrier
            float oy = offL[px * 18 + 2 * (t + 1)];
            float ox = offL[px * 18 + 2 * (t + 1) + 1];
            tp[nxt] = make_tap((float)(row + (t + 1) / 3 - 1) + oy,
                               (float)(px + (t + 1) % 3 - 1) + ox);
            int o00 = tp[nxt].i00 * 64 + q * 8;
            int o01 = tp[nxt].i01 * 64 + q * 8;
            int o10 = tp[nxt].i10 * 64 + q * 8;
            int o11 = tp[nxt].i11 * 64 + q * 8;
            gq[nxt][0] = *(const uint4*)(hb + o00);
            gq[nxt][1] = *(const uint4*)(hb + o01);
            gq[nxt][2] = *(const uint4*)(hb + o10);
            gq[nxt][3] = *(const uint4*)(hb + o11);
            gq[nxt][4] = *(const uint4*)(hb + o00 + 32);
            gq[nxt][5] = *(const uint4*)(hb + o01 + 32);
            gq[nxt][6] = *(const uint4*)(hb + o10 + 32);
            gq[nxt][7] = *(const uint4*)(hb + o11 + 32);
        }
        // interp(t) from registers (auto-wait vmcnt<=12: gq[cur] landed)
        float w00 = tp[cur].w00, w01 = tp[cur].w01;
        float w10 = tp[cur].w10, w11 = tp[cur].w11;
        bhalf8 af0, af1;
        {
            f32x4 ve = w00 * evenf(gq[cur][0]) + w01 * evenf(gq[cur][1])
                     + w10 * evenf(gq[cur][2]) + w11 * evenf(gq[cur][3]);
            f32x4 vo = w00 * oddf(gq[cur][0]) + w01 * oddf(gq[cur][1])
                     + w10 * oddf(gq[cur][2]) + w11 * oddf(gq[cur][3]);
            u32x4 uu;
            uu[0] = cvtpk_bf16(ve[0], vo[0]);
            uu[1] = cvtpk_bf16(ve[1], vo[1]);
            uu[2] = cvtpk_bf16(ve[2], vo[2]);
            uu[3] = cvtpk_bf16(ve[3], vo[3]);
            af0 = __builtin_bit_cast(bhalf8, uu);
        }
        {
            f32x4 ve = w00 * evenf(gq[cur][4]) + w01 * evenf(gq[cur][5])
                     + w10 * evenf(gq[cur][6]) + w11 * evenf(gq[cur][7]);
            f32x4 vo = w00 * oddf(gq[cur][4]) + w01 * oddf(gq[cur][5])
                     + w10 * oddf(gq[cur][6]) + w11 * oddf(gq[cur][7]);
            u32x4 uu;
            uu[0] = cvtpk_bf16(ve[0], vo[0]);
            uu[1] = cvtpk_bf16(ve[1], vo[1]);
            uu[2] = cvtpk_bf16(ve[2], vo[2]);
            uu[3] = cvtpk_bf16(ve[3], vo[3]);
            af1 = __builtin_bit_cast(bhalf8, uu);
        }
        // single barrier: stage(t) published; gathers(t+1) stay in flight
        __builtin_amdgcn_sched_barrier(0);
        if (t < 8) asm volatile("s_waitcnt vmcnt(8)" ::: "memory");
        else       asm volatile("s_waitcnt vmcnt(0)" ::: "memory");
        __builtin_amdgcn_s_barrier();
        __builtin_amdgcn_sched_barrier(0);
        if (t < 8) {
            // stage(t+1) -> Bd[nxt]: WAR-safe (all waves past barrier have
            // completed their ds_reads of Bd[nxt] in MFMA(t-1)). Latency
            // hides under MFMA(t) below; forced complete at barrier(t+1).
            const char* wsrc = (const char*)wB + (t + 1) * 16384;
            char* dst = smem + nxt * 16384 + wv * 4096;
#pragma unroll
            for (int i = 0; i < 4; ++i)
                gl_lds16(wsrc + sOff[i], dst + i * 1024);
        }
        const ushort* Bq = (const ushort*)(smem + cur * 16384);
        // T5: bias the CU scheduler toward this wave's MFMA cluster while
        // co-resident waves are in their gather/interp phases.
        __builtin_amdgcn_s_setprio(1);
#pragma unroll
        for (int nt = 0; nt < 8; ++nt) {
            int us = ((nt * 16 + r) * 64 + q * 8) ^ ((r & 7) << 3);
            bhalf8 bf = *(const bhalf8*)(Bq + us);
            acc[nt] = __builtin_amdgcn_mfma_f32_16x16x32_bf16(af0, bf, acc[nt], 0, 0, 0);
        }
#pragma unroll
        for (int nt = 0; nt < 8; ++nt) {
            int us = ((nt * 16 + r) * 64 + 32 + q * 8) ^ ((r & 7) << 3);
            bhalf8 bf = *(const bhalf8*)(Bq + us);
            acc[nt] = __builtin_amdgcn_mfma_f32_16x16x32_bf16(af1, bf, acc[nt], 0, 0, 0);
        }
        __builtin_amdgcn_s_setprio(0);
    }
    // epilogue: BN + ReLU + pool (h2 never materialized)
    const float* sc = ws + SC2;
    const float* sh = ws + SH2;
    float* pool = ws + POOL;
#pragma unroll
    for (int nt = 0; nt < 8; ++nt) {
        int col = nt * 16 + r;
        float s0 = sc[col], s1 = sh[col];
        float s = 0.f;
#pragma unroll
        for (int rr = 0; rr < 4; ++rr)
            s += fmaxf(acc[nt][rr] * s0 + s1, 0.f);
        s += __shfl_xor(s, 16);
        s += __shfl_xor(s, 32);
        if (lane < 16) atomicAdd(&pool[b * 128 + col], s);
    }
}

// ---- fused fc1+relu+fc2 ----
__global__ __launch_bounds__(256) void k_fc(
    const float* __restrict__ w1, const float* __restrict__ b1,
    const float* __restrict__ w2, const float* __restrict__ b2,
    const float* __restrict__ ws, float* __restrict__ out) {
    int b = blockIdx.x, o = threadIdx.x;
    __shared__ float pl[128];
    __shared__ float hl[256];
    if (o < 128) pl[o] = ws[POOL + b * 128 + o] * (1.f / 4096.f);
    __syncthreads();
    float s = b1[o];
    const float* wp = w1 + o * 128;
#pragma unroll 8
    for (int c = 0; c < 128; ++c) s += pl[c] * wp[c];
    hl[o] = fmaxf(s, 0.f);
    __syncthreads();
    if (o < 200) {
        float s2 = b2[o];
        const float* wp2 = w2 + o * 256;
#pragma unroll 8
        for (int c = 0; c < 256; ++c) s2 += hl[c] * wp2[c];
        out[b * 200 + o] = s2;
    }
}

extern "C" void kernel_launch(void* const* d_in, const int* in_sizes, int n_in,
                              void* d_out, int out_size, void* d_ws, size_t ws_size,
                              hipStream_t stream) {
    const float* x   = (const float*)d_in[0];
    const float* o1w = (const float*)d_in[1];
    const float* o1b = (const float*)d_in[2];
    const float* c1w = (const float*)d_in[3];
    const float* c1b = (const float*)d_in[4];
    const float* g1  = (const float*)d_in[5];
    const float* be1 = (const float*)d_in[6];
    const float* m1  = (const float*)d_in[7];
    const float* v1  = (const float*)d_in[8];
    const float* o2w = (const float*)d_in[9];
    const float* o2b = (const float*)d_in[10];
    const float* c2w = (const float*)d_in[11];
    const float* c2b = (const float*)d_in[12];
    const float* g2  = (const float*)d_in[13];
    const float* be2 = (const float*)d_in[14];
    const float* m2  = (const float*)d_in[15];
    const float* v2  = (const float*)d_in[16];
    const float* f1w = (const float*)d_in[17];
    const float* f1b = (const float*)d_in[18];
    const float* f2w = (const float*)d_in[19];
    const float* f2b = (const float*)d_in[20];
    float* ws  = (float*)d_ws;
    float* out = (float*)d_out;

    k_prep<<<900, 256, 0, stream>>>(x, o1w, c1w, o2w, c2w,
                                    c1b, g1, be1, m1, v1,
                                    c2b, g2, be2, m2, v2, ws);
    k_def1<<<512, 256, 0, stream>>>(o1b, ws);
    k_def2<<<2048, 256, 0, stream>>>(o2b, ws);
    k_fc<<<32, 256, 0, stream>>>(f1w, f1b, f2w, f2b, ws, out);
}